// Round 2
// baseline (80.650 us; speedup 1.0000x reference)
//
#include <hip/hip_runtime.h>
#include <math.h>

#define B_ROWS   8192
#define K_DIM    128
#define NBLOCKS  1024
#define NTHREADS 256
#define NWAVES   4      // 1024 blocks * 4 waves * 2 rows(half-wave each) = 8192 rows
#define JITTER   1e-6f

// Last-block-done counter. Zero-initialized at module load; the last block
// resets it to 0 before finishing, so every launch (and every rocprof
// replay) starts from 0. Lives in __device__ memory, NOT in d_ws, so the
// harness's workspace poison-fill cannot corrupt it. No spinning anywhere:
// worst-case failure is wrong output, never a hang.
__device__ int g_cnt = 0;

__device__ __forceinline__ float rcpf(float x) { return __builtin_amdgcn_rcpf(x); }

// Fused digamma / trigamma / lgamma for x in [0.5, 5).
// Fixed 6-step shift (branch-free): y = x+6 in [6.5, 11), asymptotic series there.
__device__ __forceinline__ void special3(float x, float& dg, float& tg, float& lg) {
    const float x1 = x + 1.f, x2 = x + 2.f, x3 = x + 3.f, x4 = x + 4.f, x5 = x + 5.f;
    const float r0 = rcpf(x),  r1 = rcpf(x1), r2 = rcpf(x2);
    const float r3 = rcpf(x3), r4 = rcpf(x4), r5 = rcpf(x5);
    const float y  = x + 6.f;
    const float iy = rcpf(y);
    const float f  = iy * iy;
    const float ly = __logf(y);

    const float dg_y = ly - 0.5f * iy
                     + f * (-1.f/12.f + f * (1.f/120.f + f * (-1.f/252.f)));
    dg = dg_y - (((r0 + r1) + (r2 + r3)) + (r4 + r5));

    const float tg_y = iy * (1.f + iy * (0.5f + iy * (1.f/6.f
                     + f * (-1.f/30.f + f * (1.f/42.f)))));
    tg = tg_y + (((r0*r0 + r1*r1) + (r2*r2 + r3*r3)) + (r4*r4 + r5*r5));

    const float lg_y = (y - 0.5f) * ly - y + 0.91893853320467274f
                     + iy * (1.f/12.f + f * (-1.f/360.f + f * (1.f/1260.f)));
    const float prod = ((x * x1) * (x2 * x3)) * (x4 * x5);
    lg = lg_y - __logf(prod);
}

// Large-argument direct asymptotics (args here are >= ~60).
__device__ __forceinline__ float digamma_big(float y) {
    const float iy = rcpf(y), f = iy * iy;
    return __logf(y) - 0.5f * iy - f * (1.f/12.f);
}
__device__ __forceinline__ float trigamma_big(float y) {
    const float iy = rcpf(y), f = iy * iy;
    return iy + 0.5f * f + f * iy * (1.f/6.f);
}
__device__ __forceinline__ float lgamma_big(float y) {
    const float iy = rcpf(y);
    return (y - 0.5f) * __logf(y) - y + 0.91893853320467274f + iy * (1.f/12.f);
}

// Single fused kernel: 1024 blocks x 256 threads (4 waves), TWO rows per wave
// (one per 32-lane half; each half-lane float4-loads 4 elements). Butterfly
// trees are constructed to be bitwise-identical to the previous 2-kernel
// version:
//   - float4 leaf (x+y)+(z+w)  ==  old pair-leaf butterfly step 1
//   - pair accumulators (e01)+(e23)  ==  old 4-var butterfly step 1
//   - block partial = rows summed left-to-right (old 8-rows-per-block order)
//   - final reduce = verbatim old kernel2 (float4 + double + butterfly)
// The last finishing block performs the final reduce (saves one launch).
__global__ __launch_bounds__(NTHREADS)
void iedl_fused(const float* __restrict__ alpha,
                const int* __restrict__ target,
                float* __restrict__ ws,
                float* __restrict__ out) {
    const int wave = threadIdx.x >> 6;
    const int lane = threadIdx.x & 63;
    const int hl   = lane & 31;      // lane within half-wave
    const int half = lane >> 5;      // 0: row A, 1: row B
    const int b    = blockIdx.x * (NWAVES * 2) + wave * 2 + half;

    const float4 a4 = ((const float4*)(alpha + (size_t)b * K_DIM))[hl];
    const int tgt = target[b];       // half-wave uniform

    // row sum S: leaf = (x+y)+(z+w), then 5-step butterfly within the half.
    float s = (a4.x + a4.y) + (a4.z + a4.w);
    #pragma unroll
    for (int m = 1; m < 32; m <<= 1) s += __shfl_xor(s, m);

    // alpha[tgt]: element tgt&3 from half-lane tgt>>2 of our half.
    const int   te   = tgt & 3;
    const float pick = (te == 0) ? a4.x : (te == 1) ? a4.y : (te == 2) ? a4.z : a4.w;
    const float a_t  = __shfl(pick, (lane & 32) + (tgt >> 2));

    const float s_hat  = s - a_t + 1.f;
    const float trig_s = trigamma_big(s);
    const float dg_sh  = digamma_big(s_hat);
    const float inv_s  = rcpf(s);
    const float inv_s1 = rcpf(s + 1.f);

    const float ae[4] = {a4.x, a4.y, a4.z, a4.w};
    float mse_a = 0.f, mse_b = 0.f, kl_a = 0.f, kl_b = 0.f;
    float ld_a  = 0.f, ld_b  = 0.f, iv_a = 0.f, iv_b = 0.f;
    #pragma unroll
    for (int e = 0; e < 4; ++e) {
        const int   k  = 4 * hl + e;
        const float ad = ae[e];

        float dg_a, tg_a, lg_a;
        special3(ad, dg_a, tg_a, lg_a);

        const float p   = ad * inv_s;
        const float y1  = (k == tgt) ? 1.f : 0.f;
        const float err = (y1 - p) * (y1 - p);
        const float var = p * (1.f - p) * inv_s1;
        const float w   = fmaxf(tg_a - trig_s, 1e-8f);
        const float mt  = w * (err + var);

        const float D  = tg_a + JITTER;
        const float lt = __logf(D);
        const float it = rcpf(D);
        const float kt = (k != tgt) ? (-lg_a + (ad - 1.f) * (dg_a - dg_sh)) : 0.f;

        if (e < 2) { mse_a += mt; kl_a += kt; ld_a += lt; iv_a += it; }
        else       { mse_b += mt; kl_b += kt; ld_b += lt; iv_b += it; }
    }

    // pair-combine == old butterfly step 1; then 5 steps within the half.
    float mse_sum  = mse_a + mse_b;
    float kl_sum   = kl_a  + kl_b;
    float logd_sum = ld_a  + ld_b;
    float invd_sum = iv_a  + iv_b;
    #pragma unroll
    for (int m = 1; m < 32; m <<= 1) {
        mse_sum  += __shfl_xor(mse_sum,  m);
        kl_sum   += __shfl_xor(kl_sum,   m);
        logd_sum += __shfl_xor(logd_sum, m);
        invd_sum += __shfl_xor(invd_sum, m);
    }

    // lgamma(128) = 491.5534482309...
    const float acc_kl = lgamma_big(s_hat) - 491.5534482f + kl_sum;
    // det(FIM) = prod(D) * (1 - trig_s * sum(1/D))  (diag + rank-1)
    const float t      = 1.f - trig_s * invd_sum;
    const float acc_ld = (t > 0.f) ? (logd_sum + __logf(t)) : -20.f;

    // per-block combine: rows in increasing order (matches old 8-row blocks)
    __shared__ float smp[3][NWAVES][2];
    __shared__ int   last_flag;
    if (hl == 0) {
        smp[0][wave][half] = mse_sum;
        smp[1][wave][half] = acc_kl;
        smp[2][wave][half] = acc_ld;
    }
    __syncthreads();

    if (threadIdx.x == 0) {
        float M = 0.f, KK = 0.f, L = 0.f;
        #pragma unroll
        for (int w = 0; w < NWAVES; ++w) {
            M  += smp[0][w][0]; M  += smp[0][w][1];
            KK += smp[1][w][0]; KK += smp[1][w][1];
            L  += smp[2][w][0]; L  += smp[2][w][1];
        }
        ws[blockIdx.x]               = M;
        ws[NBLOCKS + blockIdx.x]     = KK;
        ws[2 * NBLOCKS + blockIdx.x] = L;

        // release our partials, count blocks (agent scope = device scope)
        const int old = __hip_atomic_fetch_add(&g_cnt, 1, __ATOMIC_ACQ_REL,
                                               __HIP_MEMORY_SCOPE_AGENT);
        const int last = (old == NBLOCKS - 1);
        if (last) {
            // all 1024 adds observed -> reset for next launch, then make all
            // blocks' ws stores visible to this CU (L1+L2 invalidate).
            __hip_atomic_store(&g_cnt, 0, __ATOMIC_RELAXED,
                               __HIP_MEMORY_SCOPE_AGENT);
            __threadfence();
        }
        last_flag = last;
    }
    __syncthreads();
    if (!last_flag) return;

    // ---- final reduce: verbatim old iedl_reduce (256 threads) ----
    const int tid  = threadIdx.x;
    const int rwav = tid >> 6;
    const int rlan = tid & 63;

    const float4 m4 = ((const float4*)(ws))[tid];
    const float4 k4 = ((const float4*)(ws + NBLOCKS))[tid];
    const float4 l4 = ((const float4*)(ws + 2 * NBLOCKS))[tid];

    double m = ((double)m4.x + (double)m4.y) + ((double)m4.z + (double)m4.w);
    double k = ((double)k4.x + (double)k4.y) + ((double)k4.z + (double)k4.w);
    double l = ((double)l4.x + (double)l4.y) + ((double)l4.z + (double)l4.w);

    #pragma unroll
    for (int off = 1; off < 64; off <<= 1) {
        m += __shfl_xor(m, off);
        k += __shfl_xor(k, off);
        l += __shfl_xor(l, off);
    }

    __shared__ double smd[3][4];
    if (rlan == 0) { smd[0][rwav] = m; smd[1][rwav] = k; smd[2][rwav] = l; }
    __syncthreads();

    if (tid == 0) {
        double M = 0.0, KK = 0.0, L = 0.0;
        #pragma unroll
        for (int w = 0; w < 4; ++w) { M += smd[0][w]; KK += smd[1][w]; L += smd[2][w]; }
        const double inv_b = 1.0 / (double)B_ROWS;
        const double i_mse = M * inv_b;
        const double kl    = KK * inv_b;
        const double ldm   = L * inv_b;
        out[0] = (float)(i_mse + kl - 0.01 * ldm);
        out[1] = (float)i_mse;
        out[2] = (float)kl;
        out[3] = (float)ldm;
    }
}

extern "C" void kernel_launch(void* const* d_in, const int* in_sizes, int n_in,
                              void* d_out, int out_size, void* d_ws, size_t ws_size,
                              hipStream_t stream) {
    const float* alpha  = (const float*)d_in[0];
    const int*   target = (const int*)d_in[1];
    float*       out    = (float*)d_out;
    float*       ws     = (float*)d_ws;   // 3072 floats used

    iedl_fused<<<NBLOCKS, NTHREADS, 0, stream>>>(alpha, target, ws, out);
}

// Round 3
// 61.261 us; speedup vs baseline: 1.3165x; 1.3165x over previous
//
#include <hip/hip_runtime.h>
#include <hip/hip_bf16.h>
#include <math.h>

#define B_ROWS   8192
#define K_DIM    128
#define NBLOCKS  1024
#define NTHREADS 512
#define NWAVES   8      // 1024 blocks * 8 waves * 1 row = 8192 rows
#define JITTER   1e-6f

__device__ __forceinline__ float rcpf(float x) { return __builtin_amdgcn_rcpf(x); }

// Fused digamma / trigamma / lgamma for x in [0.5, 5).
// Fixed 6-step shift (branch-free): y = x+6 in [6.5, 11), asymptotic series there.
__device__ __forceinline__ void special3(float x, float& dg, float& tg, float& lg) {
    const float x1 = x + 1.f, x2 = x + 2.f, x3 = x + 3.f, x4 = x + 4.f, x5 = x + 5.f;
    const float r0 = rcpf(x),  r1 = rcpf(x1), r2 = rcpf(x2);
    const float r3 = rcpf(x3), r4 = rcpf(x4), r5 = rcpf(x5);
    const float y  = x + 6.f;
    const float iy = rcpf(y);
    const float f  = iy * iy;
    const float ly = __logf(y);

    const float dg_y = ly - 0.5f * iy
                     + f * (-1.f/12.f + f * (1.f/120.f + f * (-1.f/252.f)));
    dg = dg_y - (((r0 + r1) + (r2 + r3)) + (r4 + r5));

    const float tg_y = iy * (1.f + iy * (0.5f + iy * (1.f/6.f
                     + f * (-1.f/30.f + f * (1.f/42.f)))));
    tg = tg_y + (((r0*r0 + r1*r1) + (r2*r2 + r3*r3)) + (r4*r4 + r5*r5));

    const float lg_y = (y - 0.5f) * ly - y + 0.91893853320467274f
                     + iy * (1.f/12.f + f * (-1.f/360.f + f * (1.f/1260.f)));
    const float prod = ((x * x1) * (x2 * x3)) * (x4 * x5);
    lg = lg_y - __logf(prod);
}

// Large-argument direct asymptotics (args here are >= ~60).
__device__ __forceinline__ float digamma_big(float y) {
    const float iy = rcpf(y), f = iy * iy;
    return __logf(y) - 0.5f * iy - f * (1.f/12.f);
}
__device__ __forceinline__ float trigamma_big(float y) {
    const float iy = rcpf(y), f = iy * iy;
    return iy + 0.5f * f + f * iy * (1.f/6.f);
}
__device__ __forceinline__ float lgamma_big(float y) {
    const float iy = rcpf(y);
    return (y - 0.5f) * __logf(y) - y + 0.91893853320467274f + iy * (1.f/12.f);
}

// Kernel 1: 1024 blocks x 512 threads, ONE row per wave (8 waves/block).
// 4 blocks/CU -> up to 8 waves/SIMD. Plain stores of 3 block-partials to ws;
// kernel-launch ordering makes them visible to kernel 2. (The fused
// last-block-done variant with agent-scope atomics was 19us SLOWER —
// per-block device-scope release flushes dominate. Keep two launches.)
__global__ __launch_bounds__(NTHREADS)
void iedl_rows(const float* __restrict__ alpha,
               const int* __restrict__ target,
               float* __restrict__ ws) {
    const int wave = threadIdx.x >> 6;
    const int lane = threadIdx.x & 63;
    const int b    = blockIdx.x * NWAVES + wave;

    const float2 a2 = ((const float2*)(alpha + (size_t)b * K_DIM))[lane];
    const int tgt = target[b];

    // row sum S (butterfly; all lanes identical)
    float s = a2.x + a2.y;
    #pragma unroll
    for (int m = 1; m < 64; m <<= 1) s += __shfl_xor(s, m);

    // alpha[tgt] via shuffle from owning lane (tgt is wave-uniform)
    const float a_pick = (tgt & 1) ? a2.y : a2.x;
    const float a_t    = __shfl(a_pick, tgt >> 1);

    const float s_hat  = s - a_t + 1.f;
    const float trig_s = trigamma_big(s);
    const float dg_sh  = digamma_big(s_hat);
    const float inv_s  = rcpf(s);
    const float inv_s1 = rcpf(s + 1.f);

    float mse_sum = 0.f, kl_sum = 0.f, logd_sum = 0.f, invd_sum = 0.f;
    #pragma unroll
    for (int e = 0; e < 2; ++e) {
        const int   k  = 2 * lane + e;
        const float ad = (e == 0) ? a2.x : a2.y;

        float dg_a, tg_a, lg_a;
        special3(ad, dg_a, tg_a, lg_a);

        const float p   = ad * inv_s;
        const float y1  = (k == tgt) ? 1.f : 0.f;
        const float err = (y1 - p) * (y1 - p);
        const float var = p * (1.f - p) * inv_s1;
        const float w   = fmaxf(tg_a - trig_s, 1e-8f);
        mse_sum += w * (err + var);

        if (k != tgt) kl_sum += -lg_a + (ad - 1.f) * (dg_a - dg_sh);

        const float D = tg_a + JITTER;   // trigamma(alpha) + jitter
        logd_sum += __logf(D);
        invd_sum += rcpf(D);
    }

    #pragma unroll
    for (int m = 1; m < 64; m <<= 1) {
        mse_sum  += __shfl_xor(mse_sum,  m);
        kl_sum   += __shfl_xor(kl_sum,   m);
        logd_sum += __shfl_xor(logd_sum, m);
        invd_sum += __shfl_xor(invd_sum, m);
    }

    // lgamma(128) = 491.5534482309...
    const float acc_kl = lgamma_big(s_hat) - 491.5534482f + kl_sum;
    // det(FIM) = prod(D) * (1 - trig_s * sum(1/D))  (diag + rank-1)
    const float t      = 1.f - trig_s * invd_sum;
    const float acc_ld = (t > 0.f) ? (logd_sum + __logf(t)) : -20.f;

    // cross-wave combine, 3 plain stores per block
    __shared__ float sm[3][NWAVES];
    if (lane == 0) { sm[0][wave] = mse_sum; sm[1][wave] = acc_kl; sm[2][wave] = acc_ld; }
    __syncthreads();

    if (threadIdx.x == 0) {
        float M = 0.f, KK = 0.f, L = 0.f;
        #pragma unroll
        for (int w = 0; w < NWAVES; ++w) { M += sm[0][w]; KK += sm[1][w]; L += sm[2][w]; }
        ws[blockIdx.x]               = M;
        ws[NBLOCKS + blockIdx.x]     = KK;
        ws[2 * NBLOCKS + blockIdx.x] = L;
    }
}

// Kernel 2: one block of 256 threads (4 waves). Thread i float4-loads
// partials [4i..4i+3] of each array, fixed-order accumulate in double,
// per-wave butterfly, LDS combine across the 4 waves in fixed order.
__global__ __launch_bounds__(256)
void iedl_reduce(const float* __restrict__ ws, float* __restrict__ out) {
    const int tid  = threadIdx.x;
    const int wave = tid >> 6;
    const int lane = tid & 63;

    const float4 m4 = ((const float4*)(ws))[tid];
    const float4 k4 = ((const float4*)(ws + NBLOCKS))[tid];
    const float4 l4 = ((const float4*)(ws + 2 * NBLOCKS))[tid];

    double m = ((double)m4.x + (double)m4.y) + ((double)m4.z + (double)m4.w);
    double k = ((double)k4.x + (double)k4.y) + ((double)k4.z + (double)k4.w);
    double l = ((double)l4.x + (double)l4.y) + ((double)l4.z + (double)l4.w);

    #pragma unroll
    for (int off = 1; off < 64; off <<= 1) {
        m += __shfl_xor(m, off);
        k += __shfl_xor(k, off);
        l += __shfl_xor(l, off);
    }

    __shared__ double sm[3][4];
    if (lane == 0) { sm[0][wave] = m; sm[1][wave] = k; sm[2][wave] = l; }
    __syncthreads();

    if (tid == 0) {
        double M = 0.0, KK = 0.0, L = 0.0;
        #pragma unroll
        for (int w = 0; w < 4; ++w) { M += sm[0][w]; KK += sm[1][w]; L += sm[2][w]; }
        const double inv_b = 1.0 / (double)B_ROWS;
        const double i_mse = M * inv_b;
        const double kl    = KK * inv_b;
        const double ldm   = L * inv_b;
        out[0] = (float)(i_mse + kl - 0.01 * ldm);
        out[1] = (float)i_mse;
        out[2] = (float)kl;
        out[3] = (float)ldm;
    }
}

extern "C" void kernel_launch(void* const* d_in, const int* in_sizes, int n_in,
                              void* d_out, int out_size, void* d_ws, size_t ws_size,
                              hipStream_t stream) {
    const float* alpha  = (const float*)d_in[0];
    const int*   target = (const int*)d_in[1];
    float*       out    = (float*)d_out;
    float*       ws     = (float*)d_ws;   // 3072 floats used

    iedl_rows<<<NBLOCKS, NTHREADS, 0, stream>>>(alpha, target, ws);
    iedl_reduce<<<1, 64 * 4, 0, stream>>>(ws, out);
}